// Round 1
// baseline (14858.409 us; speedup 1.0000x reference)
//
#include <hip/hip_runtime.h>

#define EPS 1e-5f

// One thread per output row; 32 fp32 accumulators (Co=32).
// W is addressed wave-uniformly (k loop-uniform, ci/co unrolled) -> scalar loads.
// Fused BN statistics: per-wave shuffle butterfly + atomics into stats[0..31]=sum,
// stats[32..63]=sum of squares.
template <int CI, int K>
__global__ __launch_bounds__(256) void conv_kernel(
    const float* __restrict__ x, const int* __restrict__ nbr,
    const float* __restrict__ W, float* __restrict__ y,
    float* __restrict__ stats, int N)
{
    int row = blockIdx.x * 256 + threadIdx.x;
    float acc[32];
#pragma unroll
    for (int co = 0; co < 32; ++co) acc[co] = 0.0f;

    if (row < N) {
        for (int k = 0; k < K; ++k) {
            int idx = nbr[(long)k * N + row];
            if (idx >= 0) {
                const float* xr = x + (long)idx * CI;
                const float* Wk = W + k * CI * 32;
#pragma unroll
                for (int ci = 0; ci < CI; ++ci) {
                    float xv = xr[ci];
#pragma unroll
                    for (int co = 0; co < 32; ++co)
                        acc[co] = fmaf(xv, Wk[ci * 32 + co], acc[co]);
                }
            }
        }
        float* yr = y + (long)row * 32;
#pragma unroll
        for (int co = 0; co < 32; ++co) yr[co] = acc[co];
    }

    // BN stats: rows >= N hold zeros and contribute nothing.
#pragma unroll
    for (int co = 0; co < 32; ++co) {
        float s = acc[co];
        float q = s * s;
#pragma unroll
        for (int off = 32; off >= 1; off >>= 1) {
            s += __shfl_down(s, off);
            q += __shfl_down(q, off);
        }
        if ((threadIdx.x & 63) == 0) {
            atomicAdd(&stats[co], s);
            atomicAdd(&stats[32 + co], q);
        }
    }
}

// Elementwise BN (+optional residual) + ReLU. Safe fully in-place (pure elementwise).
__global__ __launch_bounds__(256) void bn_relu_kernel(
    const float* __restrict__ y, const float* __restrict__ stats,
    const float* __restrict__ gamma, const float* __restrict__ beta,
    const float* __restrict__ resid, float* __restrict__ out, int N)
{
    long i = (long)blockIdx.x * 256 + threadIdx.x;
    long total = (long)N * 32;
    if (i >= total) return;
    int co = (int)(i & 31);
    float inv_n = 1.0f / (float)N;
    float mu = stats[co] * inv_n;
    float var = stats[32 + co] * inv_n - mu * mu;
    float scale = rsqrtf(var + EPS) * gamma[co];
    float v = (y[i] - mu) * scale + beta[co];
    if (resid) v += resid[i];
    out[i] = fmaxf(v, 0.0f);
}

extern "C" void kernel_launch(void* const* d_in, const int* in_sizes, int n_in,
                              void* d_out, int out_size, void* d_ws, size_t ws_size,
                              hipStream_t stream)
{
    const float* vf   = (const float*)d_in[0];
    const float* Ws1  = (const float*)d_in[1];
    const float* Ws2  = (const float*)d_in[2];
    const float* Wd   = (const float*)d_in[3];
    const float* Wr1a = (const float*)d_in[4];
    const float* Wr1b = (const float*)d_in[5];
    const float* Wr2a = (const float*)d_in[6];
    const float* Wr2b = (const float*)d_in[7];
    const float* gam  = (const float*)d_in[8];
    const float* bet  = (const float*)d_in[9];
    const int* nbr0   = (const int*)d_in[10];
    const int* down1  = (const int*)d_in[11];
    const int* nbr1   = (const int*)d_in[12];

    int N0 = in_sizes[0] / 4;
    int N1 = in_sizes[11] / 8;

    float* bufA  = (float*)d_ws;                 // N0*32 floats
    float* bufB  = bufA + (size_t)N0 * 32;       // N0*32 floats
    float* stats = bufB + (size_t)N0 * 32;       // 7*64 floats
    float* out   = (float*)d_out;                // N1*32 floats (also used as scratch)

    hipMemsetAsync(stats, 0, 7 * 64 * sizeof(float), stream);

    auto cgrid = [](int n) { return dim3((unsigned)((n + 255) / 256)); };
    auto bgrid = [](long n) { return dim3((unsigned)((n * 32 + 255) / 256)); };

    // stem1: vf -> bufA
    conv_kernel<4, 27><<<cgrid(N0), 256, 0, stream>>>(vf, nbr0, Ws1, bufA, stats + 0 * 64, N0);
    bn_relu_kernel<<<bgrid(N0), 256, 0, stream>>>(bufA, stats + 0 * 64, gam + 0, bet + 0, nullptr, bufA, N0);
    // stem2: bufA -> bufB
    conv_kernel<32, 27><<<cgrid(N0), 256, 0, stream>>>(bufA, nbr0, Ws2, bufB, stats + 1 * 64, N0);
    bn_relu_kernel<<<bgrid(N0), 256, 0, stream>>>(bufB, stats + 1 * 64, gam + 32, bet + 32, nullptr, bufB, N0);
    // down: bufB -> bufA (x1)
    conv_kernel<32, 8><<<cgrid(N1), 256, 0, stream>>>(bufB, down1, Wd, bufA, stats + 2 * 64, N1);
    bn_relu_kernel<<<bgrid(N1), 256, 0, stream>>>(bufA, stats + 2 * 64, gam + 64, bet + 64, nullptr, bufA, N1);
    // r1a: bufA -> bufB (h)
    conv_kernel<32, 27><<<cgrid(N1), 256, 0, stream>>>(bufA, nbr1, Wr1a, bufB, stats + 3 * 64, N1);
    bn_relu_kernel<<<bgrid(N1), 256, 0, stream>>>(bufB, stats + 3 * 64, gam + 96, bet + 96, nullptr, bufB, N1);
    // r1b: bufB -> d_out (raw), then x1' = relu(bn(d_out) + bufA) -> bufA
    conv_kernel<32, 27><<<cgrid(N1), 256, 0, stream>>>(bufB, nbr1, Wr1b, out, stats + 4 * 64, N1);
    bn_relu_kernel<<<bgrid(N1), 256, 0, stream>>>(out, stats + 4 * 64, gam + 128, bet + 128, bufA, bufA, N1);
    // r2a: bufA -> bufB (h)
    conv_kernel<32, 27><<<cgrid(N1), 256, 0, stream>>>(bufA, nbr1, Wr2a, bufB, stats + 5 * 64, N1);
    bn_relu_kernel<<<bgrid(N1), 256, 0, stream>>>(bufB, stats + 5 * 64, gam + 160, bet + 160, nullptr, bufB, N1);
    // r2b: bufB -> d_out (raw), then out = relu(bn(d_out) + bufA) -> d_out
    conv_kernel<32, 27><<<cgrid(N1), 256, 0, stream>>>(bufB, nbr1, Wr2b, out, stats + 6 * 64, N1);
    bn_relu_kernel<<<bgrid(N1), 256, 0, stream>>>(out, stats + 6 * 64, gam + 192, bet + 192, bufA, out, N1);
}